// Round 5
// baseline (57.988 us; speedup 1.0000x reference)
//
#include <hip/hip_runtime.h>

#define N_IN   256
#define N_EVAL 1088
#define TOTALW 1344
#define DEG    32

typedef __attribute__((ext_vector_type(8))) short short8;
typedef __attribute__((ext_vector_type(4))) float f32x4;
typedef unsigned short u16;
typedef unsigned int   u32;

__device__ __forceinline__ u32 pk2(float lo, float hi) {
    u32 ul = __float_as_uint(lo);
    u32 uh = __float_as_uint(hi);
    ul = (ul + 0x7fffu + ((ul >> 16) & 1u)) >> 16;
    uh = (uh + 0x7fffu + ((uh >> 16) & 1u)) & 0xffff0000u;
    return ul | uh;
}
__device__ __forceinline__ u16 bf1(float v) {
    u32 u = __float_as_uint(v);
    return (u16)((u + 0x7fffu + ((u >> 16) & 1u)) >> 16);
}

// ---------------- build kernel: scatter (src,w) -> dense M in B-frag layout ----
// Layout (bf16 elems): Loff[li] + ((kt*NT + nt)*64 + lane)*8 + e
//   where lane = (g<<4)|ln, k = kt*32 + 8g + e (= source col c), j = nt*16 + ln.
__global__ __launch_bounds__(256) void build_m(
    const int* __restrict__ src, const float* __restrict__ w,
    u16* __restrict__ B)
{
    int gn = blockIdx.x * 256 + threadIdx.x;
    if (gn >= N_EVAL) return;
    const int li   = gn >> 8;
    const int nloc = gn & 255;
    const int NT   = (li < 4) ? 16 : 4;
    const int loff[5] = {0, 65536, 196608, 393216, 655360};
    const int base = loff[li];

    int c[DEG]; float ow[DEG];
    const int4*   s4 = (const int4*)(src + (size_t)gn * DEG);
    const float4* w4 = (const float4*)(w   + (size_t)gn * DEG);
    #pragma unroll
    for (int k = 0; k < 8; ++k) {
        int4 ci = s4[k]; float4 wf = w4[k];
        c[4*k+0]=ci.x; c[4*k+1]=ci.y; c[4*k+2]=ci.z; c[4*k+3]=ci.w;
        ow[4*k+0]=wf.x; ow[4*k+1]=wf.y; ow[4*k+2]=wf.z; ow[4*k+3]=wf.w;
    }
    // Duplicate source columns: accumulate full sum into LAST occurrence,
    // mark earlier occurrences dead (avoids multi-store to one address).
    float acc[DEG]; bool live[DEG];
    #pragma unroll
    for (int d = 0; d < DEG; ++d) {
        float s = 0.f;
        #pragma unroll
        for (int d2 = 0; d2 < DEG; ++d2)
            if (d2 <= d && c[d2] == c[d]) s += ow[d2];
        acc[d] = s;
        bool lv = true;
        #pragma unroll
        for (int d2 = 0; d2 < DEG; ++d2)
            if (d2 > d && c[d2] == c[d]) lv = false;
        live[d] = lv;
    }
    const int nt = nloc >> 4, ln = nloc & 15;
    #pragma unroll
    for (int d = 0; d < DEG; ++d) {
        if (!live[d]) continue;
        int cc = c[d];
        int kt = cc >> 5, ko = cc & 31;
        int lane = ((ko >> 3) << 4) | ln;
        int idx = base + ((kt * NT + nt) * 64 + lane) * 8 + (ko & 7);
        B[idx] = bf1(acc[d]);
    }
}

// ---------------- main MFMA kernel --------------------------------------------
#define TILE_B 32
#define RSTRIDE (TOTALW * 2)   // 2688 B per batch row (bf16), multiple of 128

__global__ __launch_bounds__(512) void neat_mfma(
    const float* __restrict__ x, const u16* __restrict__ Bbuf,
    const float* __restrict__ bias, const float* __restrict__ resp,
    float* __restrict__ out)
{
    __shared__ uint4 ldsq[(TILE_B * RSTRIDE) / 16];   // 86,016 B
    char* lds = (char*)ldsq;
    const int tid  = threadIdx.x;
    const int b0   = blockIdx.x * TILE_B;
    const int lane = tid & 63;
    const int wvid = tid >> 6;

    // stage x: f32 -> bf16, row-major, XOR-swizzled granules
    #pragma unroll
    for (int i = 0; i < 4; ++i) {
        int f4 = tid + i * 512;          // 2048 = 32 rows x 64 float4
        int row = f4 >> 6;
        int c4  = f4 & 63;
        float4 xv = ((const float4*)(x + (size_t)(b0 + row) * N_IN))[c4];
        u32 p0 = pk2(xv.x, xv.y), p1 = pk2(xv.z, xv.w);
        int byte = row * RSTRIDE + ((c4 * 8) ^ ((row & 7) << 4));
        *(u32*)(lds + byte)     = p0;
        *(u32*)(lds + byte + 4) = p1;
    }
    __syncthreads();

    const short8* Bf = (const short8*)Bbuf;
    const int r0  = lane & 15;
    const int r1  = r0 + 16;
    const int g16 = (lane >> 4) << 4;    // k-group byte offset
    const int sw  = (r0 & 7) << 4;       // same for r0 and r1
    const int ab0 = r0 * RSTRIDE;
    const int ab1 = r1 * RSTRIDE;

    int cbase = N_IN;
    #pragma unroll
    for (int li = 0; li < 5; ++li) {
        const int ktn = (N_IN + li * 256) >> 5;
        const int loff8[5] = {0, 8192, 24576, 49152, 81920};
        const int lo8 = loff8[li];
        const int nbase = cbase - N_IN;

        if (li < 4) {
            const int NT = 16;
            const int nt0 = wvid, nt1 = wvid + 8;
            f32x4 acc00 = {0,0,0,0}, acc01 = {0,0,0,0};
            f32x4 acc10 = {0,0,0,0}, acc11 = {0,0,0,0};
            const short8* bp0 = Bf + lo8 + nt0 * 64 + lane;
            const short8* bp1 = Bf + lo8 + nt1 * 64 + lane;
            short8 b0v = bp0[0];
            short8 b1v = bp1[0];
            for (int kt = 0; kt < ktn; ++kt) {
                int ktp = (kt + 1 < ktn) ? kt + 1 : kt;      // safe prefetch
                short8 nb0 = bp0[ktp * (NT * 64)];
                short8 nb1 = bp1[ktp * (NT * 64)];
                int inrow = (kt * 64 + g16) ^ sw;
                short8 a0 = *(const short8*)(lds + ab0 + inrow);
                short8 a1 = *(const short8*)(lds + ab1 + inrow);
                acc00 = __builtin_amdgcn_mfma_f32_16x16x32_bf16(a0, b0v, acc00, 0, 0, 0);
                acc01 = __builtin_amdgcn_mfma_f32_16x16x32_bf16(a1, b0v, acc01, 0, 0, 0);
                acc10 = __builtin_amdgcn_mfma_f32_16x16x32_bf16(a0, b1v, acc10, 0, 0, 0);
                acc11 = __builtin_amdgcn_mfma_f32_16x16x32_bf16(a1, b1v, acc11, 0, 0, 0);
                b0v = nb0; b1v = nb1;
            }
            // epilogue: bias + resp*acc, ReLU, write bf16 back to vals
            #pragma unroll
            for (int t = 0; t < 2; ++t) {
                int nt = t ? nt1 : nt0;
                f32x4 aA = t ? acc10 : acc00;    // rows 0..15
                f32x4 aB = t ? acc11 : acc01;    // rows 16..31
                int gr = nbase + nt * 16 + r0;
                float bb = bias[gr], rr = resp[gr];
                int colbyte = (cbase + nt * 16 + r0) * 2;
                #pragma unroll
                for (int r = 0; r < 4; ++r) {
                    int i0 = ((lane >> 4) << 2) + r;
                    float v0 = fmaxf(fmaf(rr, aA[r], bb), 0.f);
                    *(u16*)(lds + i0 * RSTRIDE + (colbyte ^ ((i0 & 7) << 4))) = bf1(v0);
                    int i1 = i0 + 16;
                    float v1 = fmaxf(fmaf(rr, aB[r], bb), 0.f);
                    *(u16*)(lds + i1 * RSTRIDE + (colbyte ^ ((i1 & 7) << 4))) = bf1(v1);
                }
            }
            __syncthreads();
        } else {
            // layer 4: 64 neurons = 4 n-tiles on waves 0..3, output to global f32
            const int NT = 4;
            if (wvid < 4) {
                const int nt0 = wvid;
                f32x4 acc0 = {0,0,0,0}, acc1 = {0,0,0,0};
                const short8* bp0 = Bf + lo8 + nt0 * 64 + lane;
                short8 b0v = bp0[0];
                for (int kt = 0; kt < ktn; ++kt) {
                    int ktp = (kt + 1 < ktn) ? kt + 1 : kt;
                    short8 nb0 = bp0[ktp * (NT * 64)];
                    int inrow = (kt * 64 + g16) ^ sw;
                    short8 a0 = *(const short8*)(lds + ab0 + inrow);
                    short8 a1 = *(const short8*)(lds + ab1 + inrow);
                    acc0 = __builtin_amdgcn_mfma_f32_16x16x32_bf16(a0, b0v, acc0, 0, 0, 0);
                    acc1 = __builtin_amdgcn_mfma_f32_16x16x32_bf16(a1, b0v, acc1, 0, 0, 0);
                    b0v = nb0;
                }
                int gr = nbase + nt0 * 16 + r0;
                float bb = bias[gr], rr = resp[gr];
                int col = nt0 * 16 + r0;
                #pragma unroll
                for (int r = 0; r < 4; ++r) {
                    int i0 = ((lane >> 4) << 2) + r;
                    out[(size_t)(b0 + i0) * 64 + col] = fmaxf(fmaf(rr, acc0[r], bb), 0.f);
                    int i1 = i0 + 16;
                    out[(size_t)(b0 + i1) * 64 + col] = fmaxf(fmaf(rr, acc1[r], bb), 0.f);
                }
            }
        }
        cbase += (li < 4) ? 256 : 64;
    }
}

// ---------------- R4 fallback (LDS gather, proven) ----------------------------
#define FTILE_B 16
__device__ __forceinline__ int gbyte(int c, int h) {
    return ((c << 5) + (h << 4)) ^ (int)((((unsigned)c >> 2) & 7u) << 5);
}
__device__ __forceinline__ void fmadw(u32 d, float wv, float* acc) {
    acc[0] = fmaf(__uint_as_float(d << 16), wv, acc[0]);
    acc[1] = fmaf(__uint_as_float(d & 0xffff0000u), wv, acc[1]);
}
__device__ __forceinline__ void colacc16(const u32* vals, int c, float wv, float* acc) {
    const uint4* p = (const uint4*)((const char*)vals + gbyte(c, 0));
    uint4 a = p[0]; uint4 b = p[1];
    fmadw(a.x, wv, acc + 0);  fmadw(a.y, wv, acc + 2);
    fmadw(a.z, wv, acc + 4);  fmadw(a.w, wv, acc + 6);
    fmadw(b.x, wv, acc + 8);  fmadw(b.y, wv, acc + 10);
    fmadw(b.z, wv, acc + 12); fmadw(b.w, wv, acc + 14);
}
__global__ __launch_bounds__(256) void neat_eval_r4(
    const float* __restrict__ x, const float* __restrict__ w,
    const float* __restrict__ bias, const float* __restrict__ resp,
    const int* __restrict__ src, float* __restrict__ out)
{
    __shared__ u32 vals[TOTALW * 8];
    const int tid = threadIdx.x;
    const int b0  = blockIdx.x * FTILE_B;
    #pragma unroll
    for (int i = 0; i < 2; ++i) {
        int g = tid + i * 256;
        int c = g & 255, h = g >> 8;
        u32 pk[4];
        #pragma unroll
        for (int j = 0; j < 4; ++j) {
            float lo = x[(size_t)(b0 + h * 8 + 2 * j    ) * N_IN + c];
            float hi = x[(size_t)(b0 + h * 8 + 2 * j + 1) * N_IN + c];
            pk[j] = pk2(lo, hi);
        }
        *(uint4*)((char*)vals + gbyte(c, h)) = make_uint4(pk[0], pk[1], pk[2], pk[3]);
    }
    __syncthreads();
    int row = 0, outoff = N_IN;
    #pragma unroll
    for (int li = 0; li < 5; ++li) {
        const int sz = (li < 4) ? 256 : 64;
        for (int n = tid; n < sz; n += 256) {
            const int gr = row + n;
            const int4*   s4 = (const int4*)(src + (size_t)gr * DEG);
            const float4* w4 = (const float4*)(w   + (size_t)gr * DEG);
            float acc[16];
            #pragma unroll
            for (int i = 0; i < 16; ++i) acc[i] = 0.f;
            #pragma unroll
            for (int k = 0; k < DEG / 4; ++k) {
                int4 i4 = s4[k]; float4 wv = w4[k];
                colacc16(vals, i4.x, wv.x, acc);
                colacc16(vals, i4.y, wv.y, acc);
                colacc16(vals, i4.z, wv.z, acc);
                colacc16(vals, i4.w, wv.w, acc);
            }
            const float bb = bias[gr], rr = resp[gr];
            u32 pk[8];
            #pragma unroll
            for (int j = 0; j < 8; ++j) {
                float lo = fmaxf(fmaf(rr, acc[2 * j    ], bb), 0.f);
                float hi = fmaxf(fmaf(rr, acc[2 * j + 1], bb), 0.f);
                pk[j] = pk2(lo, hi);
            }
            int ob = gbyte(outoff + n, 0);
            *(uint4*)((char*)vals + ob)      = make_uint4(pk[0], pk[1], pk[2], pk[3]);
            *(uint4*)((char*)vals + ob + 16) = make_uint4(pk[4], pk[5], pk[6], pk[7]);
        }
        __syncthreads();
        row += sz; outoff += sz;
    }
    #pragma unroll
    for (int i = 0; i < 4; ++i) {
        int idx = tid + i * 256;
        int c = idx & 63, b = idx >> 6;
        int col = TOTALW - 64 + c;
        const u32* g = (const u32*)((const char*)vals + gbyte(col, b >> 3));
        u32 d = g[(b & 7) >> 1];
        float v = (b & 1) ? __uint_as_float(d & 0xffff0000u)
                          : __uint_as_float(d << 16);
        out[(size_t)(b0 + b) * 64 + c] = v;
    }
}

extern "C" void kernel_launch(void* const* d_in, const int* in_sizes, int n_in,
                              void* d_out, int out_size, void* d_ws, size_t ws_size,
                              hipStream_t stream) {
    const float* x    = (const float*)d_in[0];
    const float* w    = (const float*)d_in[1];
    const float* bias = (const float*)d_in[2];
    const float* resp = (const float*)d_in[3];
    const int*   src  = (const int*)d_in[4];
    float* out = (float*)d_out;

    const int batch = in_sizes[0] / N_IN;            // 8192
    const size_t need = 737280ull * 2;               // dense M, bf16

    if (ws_size >= need && (batch % TILE_B) == 0) {
        u16* Bbuf = (u16*)d_ws;
        hipMemsetAsync(d_ws, 0, need, stream);
        build_m<<<(N_EVAL + 255) / 256, 256, 0, stream>>>(src, w, Bbuf);
        neat_mfma<<<batch / TILE_B, 512, 0, stream>>>(x, Bbuf, bias, resp, out);
    } else {
        neat_eval_r4<<<batch / FTILE_B, 256, 0, stream>>>(x, w, bias, resp, src, out);
    }
}

// Round 6
// 40.681 us; speedup vs baseline: 1.4254x; 1.4254x over previous
//
#include <hip/hip_runtime.h>

#define N_IN   256
#define N_EVAL 1088
#define TOTALW 1344
#define DEG    32

typedef __attribute__((ext_vector_type(8))) short short8;
typedef __attribute__((ext_vector_type(4))) float f32x4;
typedef unsigned short u16;
typedef unsigned int   u32;

__device__ __forceinline__ u32 pk2(float lo, float hi) {
    u32 ul = __float_as_uint(lo);
    u32 uh = __float_as_uint(hi);
    ul = (ul + 0x7fffu + ((ul >> 16) & 1u)) >> 16;
    uh = (uh + 0x7fffu + ((uh >> 16) & 1u)) & 0xffff0000u;
    return ul | uh;
}
__device__ __forceinline__ u16 bf1(float v) {
    u32 u = __float_as_uint(v);
    return (u16)((u + 0x7fffu + ((u >> 16) & 1u)) >> 16);
}

// ---------------- dense build: one thread per (neuron, k-tile) ----------------
// Writes EVERY element of B (zeros included) -> no memset, no scatter hazards.
// B layout (bf16 elems): loff[li] + ((kt*NT + nt)*64 + lane)*8 + e
//   lane = (g<<4)|ln, k = kt*32 + 8g + e, n = nt*16 + ln.
__global__ __launch_bounds__(256) void build_dense(
    const int* __restrict__ src, const float* __restrict__ w,
    u16* __restrict__ B)
{
    int t = blockIdx.x * 256 + threadIdx.x;          // 0..23039
    if (t >= 23040) return;
    int li, rem;
    if      (t < 2048)  { li = 0; rem = t;         }
    else if (t < 6144)  { li = 1; rem = t - 2048;  }
    else if (t < 12288) { li = 2; rem = t - 6144;  }
    else if (t < 20480) { li = 3; rem = t - 12288; }
    else                { li = 4; rem = t - 20480; }
    const int ktn  = 8 * (li + 1);                   // 8,16,24,32,40
    const int nloc = rem / ktn;
    const int kt   = rem % ktn;
    const int gn   = li * 256 + nloc;
    const int NT   = (li < 4) ? 16 : 4;
    const int loff[5] = {0, 65536, 196608, 393216, 655360};
    const int base = loff[li];

    int c[DEG]; float ow[DEG];
    const int4*   s4 = (const int4*)(src + (size_t)gn * DEG);
    const float4* w4 = (const float4*)(w   + (size_t)gn * DEG);
    #pragma unroll
    for (int k = 0; k < 8; ++k) {
        int4 ci = s4[k]; float4 wf = w4[k];
        c[4*k+0]=ci.x; c[4*k+1]=ci.y; c[4*k+2]=ci.z; c[4*k+3]=ci.w;
        ow[4*k+0]=wf.x; ow[4*k+1]=wf.y; ow[4*k+2]=wf.z; ow[4*k+3]=wf.w;
    }
    const int k0 = kt * 32;
    float v[32];
    #pragma unroll
    for (int kk = 0; kk < 32; ++kk) {
        float s = 0.f;
        #pragma unroll
        for (int d = 0; d < DEG; ++d)
            s += (c[d] == k0 + kk) ? ow[d] : 0.f;    // duplicates accumulate
        v[kk] = s;
    }
    const int nt = nloc >> 4, ln = nloc & 15;
    #pragma unroll
    for (int g = 0; g < 4; ++g) {
        int lane = (g << 4) | ln;
        int idx  = base + ((kt * NT + nt) * 64 + lane) * 8;
        uint4 pk = make_uint4(pk2(v[g*8+0], v[g*8+1]), pk2(v[g*8+2], v[g*8+3]),
                              pk2(v[g*8+4], v[g*8+5]), pk2(v[g*8+6], v[g*8+7]));
        *(uint4*)(B + idx) = pk;
    }
}

// ---------------- main MFMA kernel --------------------------------------------
#define TILE_B 32
#define LDSCOLS 1280                 // layer-4 output goes straight to global
#define RSTRIDE (LDSCOLS * 2)        // 2560 B/row, multiple of 128 -> bank-phase 0

__global__ __launch_bounds__(512) void neat_mfma(
    const float* __restrict__ x, const u16* __restrict__ Bbuf,
    const float* __restrict__ bias, const float* __restrict__ resp,
    float* __restrict__ out)
{
    __shared__ uint4 ldsq[(TILE_B * RSTRIDE) / 16];   // 81,920 B
    char* lds = (char*)ldsq;
    const int tid  = threadIdx.x;
    const int b0   = blockIdx.x * TILE_B;
    const int lane = tid & 63;
    const int wvid = tid >> 6;

    const short8* Bf = (const short8*)Bbuf;
    // issue layer-0 B prefetch (depth 2) BEFORE staging barrier
    const short8* pre0 = Bf + 0 + wvid * 64 + lane;          // nt0 = wvid, NT=16
    const short8* pre1 = Bf + 0 + (wvid + 8) * 64 + lane;    // nt1 = wvid+8
    short8 L0c0 = pre0[0],        L0c1 = pre1[0];
    short8 L0n0 = pre0[16 * 64],  L0n1 = pre1[16 * 64];

    // stage x: f32 -> bf16, row-major, XOR-swizzled 16B granules
    #pragma unroll
    for (int i = 0; i < 4; ++i) {
        int f4 = tid + i * 512;          // 2048 = 32 rows x 64 float4
        int row = f4 >> 6;
        int c4  = f4 & 63;
        float4 xv = ((const float4*)(x + (size_t)(b0 + row) * N_IN))[c4];
        u32 p0 = pk2(xv.x, xv.y), p1 = pk2(xv.z, xv.w);
        int byte = row * RSTRIDE + ((c4 * 8) ^ ((row & 7) << 4));
        *(u32*)(lds + byte)     = p0;
        *(u32*)(lds + byte + 4) = p1;
    }
    __syncthreads();

    const int r0  = lane & 15;
    const int g16 = (lane >> 4) << 4;
    const int sw  = (r0 & 7) << 4;
    const int ab0 = r0 * RSTRIDE;
    const int ab1 = (r0 + 16) * RSTRIDE;

    int cbase = N_IN;
    #pragma unroll
    for (int li = 0; li < 5; ++li) {
        const int ktn = (N_IN + li * 256) >> 5;      // 8,16,24,32,40
        const int loff8[5] = {0, 8192, 24576, 49152, 81920};
        const int lo8 = loff8[li];
        const int nbase = cbase - N_IN;

        if (li < 4) {
            const int NT = 16;
            const int nt0 = wvid, nt1 = wvid + 8;
            f32x4 acc00 = {0,0,0,0}, acc01 = {0,0,0,0};
            f32x4 acc10 = {0,0,0,0}, acc11 = {0,0,0,0};
            const short8* bp0 = Bf + lo8 + nt0 * 64 + lane;
            const short8* bp1 = Bf + lo8 + nt1 * 64 + lane;
            short8 bc0, bc1, bn0, bn1;
            if (li == 0) { bc0 = L0c0; bc1 = L0c1; bn0 = L0n0; bn1 = L0n1; }
            else         { bc0 = bp0[0]; bc1 = bp1[0];
                           bn0 = bp0[NT * 64]; bn1 = bp1[NT * 64]; }
            for (int kt = 0; kt < ktn; ++kt) {
                int kt2 = (kt + 2 < ktn) ? kt + 2 : ktn - 1;
                short8 bf0 = bp0[kt2 * (NT * 64)];
                short8 bf1 = bp1[kt2 * (NT * 64)];
                int inrow = (kt * 64 + g16) ^ sw;
                short8 a0 = *(const short8*)(lds + ab0 + inrow);
                short8 a1 = *(const short8*)(lds + ab1 + inrow);
                acc00 = __builtin_amdgcn_mfma_f32_16x16x32_bf16(a0, bc0, acc00, 0, 0, 0);
                acc01 = __builtin_amdgcn_mfma_f32_16x16x32_bf16(a1, bc0, acc01, 0, 0, 0);
                acc10 = __builtin_amdgcn_mfma_f32_16x16x32_bf16(a0, bc1, acc10, 0, 0, 0);
                acc11 = __builtin_amdgcn_mfma_f32_16x16x32_bf16(a1, bc1, acc11, 0, 0, 0);
                bc0 = bn0; bc1 = bn1; bn0 = bf0; bn1 = bf1;
            }
            #pragma unroll
            for (int t = 0; t < 2; ++t) {
                int nt = t ? nt1 : nt0;
                f32x4 aA = t ? acc10 : acc00;    // rows 0..15
                f32x4 aB = t ? acc11 : acc01;    // rows 16..31
                int gr = nbase + nt * 16 + r0;
                float bb = bias[gr], rr = resp[gr];
                int colbyte = (cbase + nt * 16 + r0) * 2;
                #pragma unroll
                for (int r = 0; r < 4; ++r) {
                    int i0 = ((lane >> 4) << 2) + r;
                    float v0 = fmaxf(fmaf(rr, aA[r], bb), 0.f);
                    *(u16*)(lds + i0 * RSTRIDE + (colbyte ^ ((i0 & 7) << 4))) = bf1(v0);
                    int i1 = i0 + 16;
                    float v1 = fmaxf(fmaf(rr, aB[r], bb), 0.f);
                    *(u16*)(lds + i1 * RSTRIDE + (colbyte ^ ((i1 & 7) << 4))) = bf1(v1);
                }
            }
            __syncthreads();
        } else {
            const int NT = 4;
            if (wvid < 4) {
                const int nt0 = wvid;
                f32x4 acc0 = {0,0,0,0}, acc1 = {0,0,0,0};
                const short8* bp0 = Bf + lo8 + nt0 * 64 + lane;
                short8 bc0 = bp0[0];
                short8 bn0 = bp0[NT * 64];
                for (int kt = 0; kt < ktn; ++kt) {
                    int kt2 = (kt + 2 < ktn) ? kt + 2 : ktn - 1;
                    short8 bf0 = bp0[kt2 * (NT * 64)];
                    int inrow = (kt * 64 + g16) ^ sw;
                    short8 a0 = *(const short8*)(lds + ab0 + inrow);
                    short8 a1 = *(const short8*)(lds + ab1 + inrow);
                    acc0 = __builtin_amdgcn_mfma_f32_16x16x32_bf16(a0, bc0, acc0, 0, 0, 0);
                    acc1 = __builtin_amdgcn_mfma_f32_16x16x32_bf16(a1, bc0, acc1, 0, 0, 0);
                    bc0 = bn0; bn0 = bf0;
                }
                int gr = nbase + nt0 * 16 + r0;
                float bb = bias[gr], rr = resp[gr];
                int col = nt0 * 16 + r0;
                #pragma unroll
                for (int r = 0; r < 4; ++r) {
                    int i0 = ((lane >> 4) << 2) + r;
                    out[(size_t)(b0 + i0) * 64 + col] = fmaxf(fmaf(rr, acc0[r], bb), 0.f);
                    int i1 = i0 + 16;
                    out[(size_t)(b0 + i1) * 64 + col] = fmaxf(fmaf(rr, acc1[r], bb), 0.f);
                }
            }
        }
        cbase += 256;
    }
}

// ---------------- R4 fallback (LDS gather, proven) ----------------------------
#define FTILE_B 16
__device__ __forceinline__ int gbyte(int c, int h) {
    return ((c << 5) + (h << 4)) ^ (int)((((unsigned)c >> 2) & 7u) << 5);
}
__device__ __forceinline__ void fmadw(u32 d, float wv, float* acc) {
    acc[0] = fmaf(__uint_as_float(d << 16), wv, acc[0]);
    acc[1] = fmaf(__uint_as_float(d & 0xffff0000u), wv, acc[1]);
}
__device__ __forceinline__ void colacc16(const u32* vals, int c, float wv, float* acc) {
    const uint4* p = (const uint4*)((const char*)vals + gbyte(c, 0));
    uint4 a = p[0]; uint4 b = p[1];
    fmadw(a.x, wv, acc + 0);  fmadw(a.y, wv, acc + 2);
    fmadw(a.z, wv, acc + 4);  fmadw(a.w, wv, acc + 6);
    fmadw(b.x, wv, acc + 8);  fmadw(b.y, wv, acc + 10);
    fmadw(b.z, wv, acc + 12); fmadw(b.w, wv, acc + 14);
}
__global__ __launch_bounds__(256) void neat_eval_r4(
    const float* __restrict__ x, const float* __restrict__ w,
    const float* __restrict__ bias, const float* __restrict__ resp,
    const int* __restrict__ src, float* __restrict__ out)
{
    __shared__ u32 vals[TOTALW * 8];
    const int tid = threadIdx.x;
    const int b0  = blockIdx.x * FTILE_B;
    #pragma unroll
    for (int i = 0; i < 2; ++i) {
        int g = tid + i * 256;
        int c = g & 255, h = g >> 8;
        u32 pk[4];
        #pragma unroll
        for (int j = 0; j < 4; ++j) {
            float lo = x[(size_t)(b0 + h * 8 + 2 * j    ) * N_IN + c];
            float hi = x[(size_t)(b0 + h * 8 + 2 * j + 1) * N_IN + c];
            pk[j] = pk2(lo, hi);
        }
        *(uint4*)((char*)vals + gbyte(c, h)) = make_uint4(pk[0], pk[1], pk[2], pk[3]);
    }
    __syncthreads();
    int row = 0, outoff = N_IN;
    #pragma unroll
    for (int li = 0; li < 5; ++li) {
        const int sz = (li < 4) ? 256 : 64;
        for (int n = tid; n < sz; n += 256) {
            const int gr = row + n;
            const int4*   s4 = (const int4*)(src + (size_t)gr * DEG);
            const float4* w4 = (const float4*)(w   + (size_t)gr * DEG);
            float acc[16];
            #pragma unroll
            for (int i = 0; i < 16; ++i) acc[i] = 0.f;
            #pragma unroll
            for (int k = 0; k < DEG / 4; ++k) {
                int4 i4 = s4[k]; float4 wv = w4[k];
                colacc16(vals, i4.x, wv.x, acc);
                colacc16(vals, i4.y, wv.y, acc);
                colacc16(vals, i4.z, wv.z, acc);
                colacc16(vals, i4.w, wv.w, acc);
            }
            const float bb = bias[gr], rr = resp[gr];
            u32 pk[8];
            #pragma unroll
            for (int j = 0; j < 8; ++j) {
                float lo = fmaxf(fmaf(rr, acc[2 * j    ], bb), 0.f);
                float hi = fmaxf(fmaf(rr, acc[2 * j + 1], bb), 0.f);
                pk[j] = pk2(lo, hi);
            }
            int ob = gbyte(outoff + n, 0);
            *(uint4*)((char*)vals + ob)      = make_uint4(pk[0], pk[1], pk[2], pk[3]);
            *(uint4*)((char*)vals + ob + 16) = make_uint4(pk[4], pk[5], pk[6], pk[7]);
        }
        __syncthreads();
        row += sz; outoff += sz;
    }
    #pragma unroll
    for (int i = 0; i < 4; ++i) {
        int idx = tid + i * 256;
        int c = idx & 63, b = idx >> 6;
        int col = TOTALW - 64 + c;
        const u32* g = (const u32*)((const char*)vals + gbyte(col, b >> 3));
        u32 d = g[(b & 7) >> 1];
        float v = (b & 1) ? __uint_as_float(d & 0xffff0000u)
                          : __uint_as_float(d << 16);
        out[(size_t)(b0 + b) * 64 + c] = v;
    }
}

extern "C" void kernel_launch(void* const* d_in, const int* in_sizes, int n_in,
                              void* d_out, int out_size, void* d_ws, size_t ws_size,
                              hipStream_t stream) {
    const float* x    = (const float*)d_in[0];
    const float* w    = (const float*)d_in[1];
    const float* bias = (const float*)d_in[2];
    const float* resp = (const float*)d_in[3];
    const int*   src  = (const int*)d_in[4];
    float* out = (float*)d_out;

    const int batch = in_sizes[0] / N_IN;            // 8192
    const size_t need = 737280ull * 2;               // dense B, bf16

    if (ws_size >= need && (batch % TILE_B) == 0) {
        u16* Bbuf = (u16*)d_ws;
        build_dense<<<90, 256, 0, stream>>>(src, w, Bbuf);
        neat_mfma<<<batch / TILE_B, 512, 0, stream>>>(x, Bbuf, bias, resp, out);
    } else {
        neat_eval_r4<<<batch / FTILE_B, 256, 0, stream>>>(x, w, bias, resp, src, out);
    }
}

// Round 7
// 30.091 us; speedup vs baseline: 1.9271x; 1.3519x over previous
//
#include <hip/hip_runtime.h>

#define N_IN   256
#define N_EVAL 1088
#define TOTALW 1344
#define DEG    32

typedef __attribute__((ext_vector_type(8))) short short8;
typedef __attribute__((ext_vector_type(4))) float f32x4;
typedef unsigned short u16;
typedef unsigned int   u32;

__device__ __forceinline__ u32 pk2(float lo, float hi) {
    u32 ul = __float_as_uint(lo);
    u32 uh = __float_as_uint(hi);
    ul = (ul + 0x7fffu + ((ul >> 16) & 1u)) >> 16;
    uh = (uh + 0x7fffu + ((uh >> 16) & 1u)) & 0xffff0000u;
    return ul | uh;
}
__device__ __forceinline__ u16 bf1(float v) {
    u32 u = __float_as_uint(v);
    return (u16)((u + 0x7fffu + ((u >> 16) & 1u)) >> 16);
}

// ---------------- dense build, 4-way split: thread = (neuron, kt, 8-k slice) --
// 92160 threads; writes every B element exactly once (no memset needed).
__global__ __launch_bounds__(256) void build_dense4(
    const int* __restrict__ src, const float* __restrict__ w,
    u16* __restrict__ B)
{
    int t = blockIdx.x * 256 + threadIdx.x;          // 0..92159
    int g  = t / 23040;                              // 8-k slice 0..3
    int tt = t - g * 23040;
    int li, nloc, kt, base, NT;
    if      (tt < 2048)  { li = 0; int r = tt;         nloc = r >> 3; kt = r & 7;  base = 0;      NT = 16; }
    else if (tt < 6144)  { li = 1; int r = tt - 2048;  nloc = r >> 4; kt = r & 15; base = 65536;  NT = 16; }
    else if (tt < 12288) { li = 2; int r = tt - 6144;  nloc = r / 24; kt = r % 24; base = 196608; NT = 16; }
    else if (tt < 20480) { li = 3; int r = tt - 12288; nloc = r >> 5; kt = r & 31; base = 393216; NT = 16; }
    else                 { li = 4; int r = tt - 20480; nloc = r / 40; kt = r % 40; base = 655360; NT = 4;  }
    const int gn = li * 256 + nloc;

    int c[DEG]; float ow[DEG];
    const int4*   s4 = (const int4*)(src + (size_t)gn * DEG);
    const float4* w4 = (const float4*)(w   + (size_t)gn * DEG);
    #pragma unroll
    for (int k = 0; k < 8; ++k) {
        int4 ci = s4[k]; float4 wf = w4[k];
        c[4*k+0]=ci.x; c[4*k+1]=ci.y; c[4*k+2]=ci.z; c[4*k+3]=ci.w;
        ow[4*k+0]=wf.x; ow[4*k+1]=wf.y; ow[4*k+2]=wf.z; ow[4*k+3]=wf.w;
    }
    const int k0 = kt * 32 + g * 8;
    float v[8];
    #pragma unroll
    for (int kk = 0; kk < 8; ++kk) {
        float s = 0.f;
        #pragma unroll
        for (int d = 0; d < DEG; ++d)
            s += (c[d] == k0 + kk) ? ow[d] : 0.f;    // duplicates accumulate
        v[kk] = s;
    }
    const int nt = nloc >> 4, ln = nloc & 15;
    const int lane = (g << 4) | ln;
    const int idx  = base + ((kt * NT + nt) * 64 + lane) * 8;
    uint4 pk = make_uint4(pk2(v[0], v[1]), pk2(v[2], v[3]),
                          pk2(v[4], v[5]), pk2(v[6], v[7]));
    *(uint4*)(B + idx) = pk;
}

// ---------------- main MFMA kernel --------------------------------------------
#define TILE_B 32
#define LDSCOLS 1280
#define RSTRIDE (LDSCOLS * 2)        // 2560 B/row

#define MFMA(a, b, c) __builtin_amdgcn_mfma_f32_16x16x32_bf16(a, b, c, 0, 0, 0)

__global__ __launch_bounds__(512) void neat_mfma(
    const float* __restrict__ x, const u16* __restrict__ Bbuf,
    const float* __restrict__ bias, const float* __restrict__ resp,
    float* __restrict__ out)
{
    __shared__ uint4 ldsq[(TILE_B * RSTRIDE) / 16];   // 81,920 B
    __shared__ f32x4 pbuf[4 * 64 * 2];                // 8,192 B (layer-4 partials)
    char* lds = (char*)ldsq;
    const int tid  = threadIdx.x;
    const int b0   = blockIdx.x * TILE_B;
    const int lane = tid & 63;
    const int wvid = tid >> 6;

    const short8* Bf = (const short8*)Bbuf;
    // layer-0 B prefetch, depth 4, issued BEFORE the staging barrier
    const short8* pre0 = Bf + wvid * 64 + lane;           // nt0 = wvid, NT=16
    const short8* pre1 = Bf + (wvid + 8) * 64 + lane;     // nt1 = wvid+8
    short8 L00 = pre0[0], L01 = pre0[1024], L02 = pre0[2048], L03 = pre0[3072];
    short8 L10 = pre1[0], L11 = pre1[1024], L12 = pre1[2048], L13 = pre1[3072];

    // stage x: f32 -> bf16, row-major, XOR-swizzled 16B granules
    #pragma unroll
    for (int i = 0; i < 4; ++i) {
        int f4 = tid + i * 512;          // 2048 = 32 rows x 64 float4
        int row = f4 >> 6;
        int c4  = f4 & 63;
        float4 xv = ((const float4*)(x + (size_t)(b0 + row) * N_IN))[c4];
        u32 p0 = pk2(xv.x, xv.y), p1 = pk2(xv.z, xv.w);
        int byte = row * RSTRIDE + ((c4 * 8) ^ ((row & 7) << 4));
        *(u32*)(lds + byte)     = p0;
        *(u32*)(lds + byte + 4) = p1;
    }
    __syncthreads();

    const int r0  = lane & 15;
    const int g16 = (lane >> 4) << 4;
    const int sw  = (r0 & 7) << 4;
    const int ab0 = r0 * RSTRIDE;
    const int ab1 = (r0 + 16) * RSTRIDE;

    int cbase = N_IN;
    #pragma unroll
    for (int li = 0; li < 5; ++li) {
        const int ktn = (N_IN + li * 256) >> 5;      // 8,16,24,32,40
        const int loff8[5] = {0, 8192, 24576, 49152, 81920};
        const int lo8 = loff8[li];
        const int nbase = cbase - N_IN;

        if (li < 4) {
            const int STEP = 16 * 64;                // NT=16
            const int nt0 = wvid, nt1 = wvid + 8;
            f32x4 acc00 = {0,0,0,0}, acc01 = {0,0,0,0};
            f32x4 acc10 = {0,0,0,0}, acc11 = {0,0,0,0};
            const short8* bp0 = Bf + lo8 + nt0 * 64 + lane;
            const short8* bp1 = Bf + lo8 + nt1 * 64 + lane;
            short8 p00, p01, p02, p03, p10, p11, p12, p13;
            if (li == 0) {
                p00 = L00; p01 = L01; p02 = L02; p03 = L03;
                p10 = L10; p11 = L11; p12 = L12; p13 = L13;
            } else {
                p00 = bp0[0]; p01 = bp0[STEP]; p02 = bp0[2*STEP]; p03 = bp0[3*STEP];
                p10 = bp1[0]; p11 = bp1[STEP]; p12 = bp1[2*STEP]; p13 = bp1[3*STEP];
            }
            for (int kt4 = 0; kt4 < ktn; kt4 += 4) {
                #pragma unroll
                for (int j = 0; j < 4; ++j) {
                    int kt  = kt4 + j;
                    int ktp = kt + 4; if (ktp >= ktn) ktp = ktn - 1;
                    short8 f0 = bp0[ktp * STEP];
                    short8 f1 = bp1[ktp * STEP];
                    int inrow = (kt * 64 + g16) ^ sw;
                    short8 a0 = *(const short8*)(lds + ab0 + inrow);
                    short8 a1 = *(const short8*)(lds + ab1 + inrow);
                    short8 b0v = (j == 0) ? p00 : (j == 1) ? p01 : (j == 2) ? p02 : p03;
                    short8 b1v = (j == 0) ? p10 : (j == 1) ? p11 : (j == 2) ? p12 : p13;
                    acc00 = MFMA(a0, b0v, acc00);
                    acc01 = MFMA(a1, b0v, acc01);
                    acc10 = MFMA(a0, b1v, acc10);
                    acc11 = MFMA(a1, b1v, acc11);
                    if      (j == 0) { p00 = f0; p10 = f1; }
                    else if (j == 1) { p01 = f0; p11 = f1; }
                    else if (j == 2) { p02 = f0; p12 = f1; }
                    else             { p03 = f0; p13 = f1; }
                }
            }
            #pragma unroll
            for (int t = 0; t < 2; ++t) {
                int nt = t ? nt1 : nt0;
                f32x4 aA = t ? acc10 : acc00;    // rows 0..15
                f32x4 aB = t ? acc11 : acc01;    // rows 16..31
                int gr = nbase + nt * 16 + r0;
                float bb = bias[gr], rr = resp[gr];
                int colbyte = (cbase + nt * 16 + r0) * 2;
                #pragma unroll
                for (int r = 0; r < 4; ++r) {
                    int i0 = ((lane >> 4) << 2) + r;
                    float v0 = fmaxf(fmaf(rr, aA[r], bb), 0.f);
                    *(u16*)(lds + i0 * RSTRIDE + (colbyte ^ ((i0 & 7) << 4))) = bf1(v0);
                    int i1 = i0 + 16;
                    float v1 = fmaxf(fmaf(rr, aB[r], bb), 0.f);
                    *(u16*)(lds + i1 * RSTRIDE + (colbyte ^ ((i1 & 7) << 4))) = bf1(v1);
                }
            }
            __syncthreads();
        } else {
            // layer 4: 64 neurons, ktn=40. All 8 waves: nt = wvid&3,
            // waves 0-3 do kt 0..19, waves 4-7 do kt 20..39; LDS reduction.
            const int STEP = 4 * 64;                 // NT=4
            const int nt0   = wvid & 3;
            const int ktbeg = (wvid >> 2) * 20;
            const int ktend = ktbeg + 20;
            f32x4 acc0 = {0,0,0,0}, acc1 = {0,0,0,0};
            const short8* bp0 = Bf + lo8 + nt0 * 64 + lane;
            short8 p00 = bp0[(ktbeg + 0) * STEP];
            short8 p01 = bp0[(ktbeg + 1) * STEP];
            short8 p02 = bp0[(ktbeg + 2) * STEP];
            short8 p03 = bp0[(ktbeg + 3) * STEP];
            for (int kt4 = ktbeg; kt4 < ktend; kt4 += 4) {
                #pragma unroll
                for (int j = 0; j < 4; ++j) {
                    int kt  = kt4 + j;
                    int ktp = kt + 4; if (ktp >= ktend) ktp = ktend - 1;
                    short8 f0 = bp0[ktp * STEP];
                    int inrow = (kt * 64 + g16) ^ sw;
                    short8 a0 = *(const short8*)(lds + ab0 + inrow);
                    short8 a1 = *(const short8*)(lds + ab1 + inrow);
                    short8 b0v = (j == 0) ? p00 : (j == 1) ? p01 : (j == 2) ? p02 : p03;
                    acc0 = MFMA(a0, b0v, acc0);
                    acc1 = MFMA(a1, b0v, acc1);
                    if      (j == 0) p00 = f0;
                    else if (j == 1) p01 = f0;
                    else if (j == 2) p02 = f0;
                    else             p03 = f0;
                }
            }
            if (wvid >= 4) {
                pbuf[((wvid - 4) * 64 + lane) * 2 + 0] = acc0;
                pbuf[((wvid - 4) * 64 + lane) * 2 + 1] = acc1;
            }
            __syncthreads();
            if (wvid < 4) {
                f32x4 q0 = pbuf[(wvid * 64 + lane) * 2 + 0];
                f32x4 q1 = pbuf[(wvid * 64 + lane) * 2 + 1];
                acc0 += q0; acc1 += q1;
                int gr = nbase + nt0 * 16 + r0;
                float bb = bias[gr], rr = resp[gr];
                int col = nt0 * 16 + r0;
                #pragma unroll
                for (int r = 0; r < 4; ++r) {
                    int i0 = ((lane >> 4) << 2) + r;
                    out[(size_t)(b0 + i0) * 64 + col] = fmaxf(fmaf(rr, acc0[r], bb), 0.f);
                    int i1 = i0 + 16;
                    out[(size_t)(b0 + i1) * 64 + col] = fmaxf(fmaf(rr, acc1[r], bb), 0.f);
                }
            }
        }
        cbase += 256;
    }
}

// ---------------- R4 fallback (LDS gather, proven) ----------------------------
#define FTILE_B 16
__device__ __forceinline__ int gbyte(int c, int h) {
    return ((c << 5) + (h << 4)) ^ (int)((((unsigned)c >> 2) & 7u) << 5);
}
__device__ __forceinline__ void fmadw(u32 d, float wv, float* acc) {
    acc[0] = fmaf(__uint_as_float(d << 16), wv, acc[0]);
    acc[1] = fmaf(__uint_as_float(d & 0xffff0000u), wv, acc[1]);
}
__device__ __forceinline__ void colacc16(const u32* vals, int c, float wv, float* acc) {
    const uint4* p = (const uint4*)((const char*)vals + gbyte(c, 0));
    uint4 a = p[0]; uint4 b = p[1];
    fmadw(a.x, wv, acc + 0);  fmadw(a.y, wv, acc + 2);
    fmadw(a.z, wv, acc + 4);  fmadw(a.w, wv, acc + 6);
    fmadw(b.x, wv, acc + 8);  fmadw(b.y, wv, acc + 10);
    fmadw(b.z, wv, acc + 12); fmadw(b.w, wv, acc + 14);
}
__global__ __launch_bounds__(256) void neat_eval_r4(
    const float* __restrict__ x, const float* __restrict__ w,
    const float* __restrict__ bias, const float* __restrict__ resp,
    const int* __restrict__ src, float* __restrict__ out)
{
    __shared__ u32 vals[TOTALW * 8];
    const int tid = threadIdx.x;
    const int b0  = blockIdx.x * FTILE_B;
    #pragma unroll
    for (int i = 0; i < 2; ++i) {
        int g = tid + i * 256;
        int c = g & 255, h = g >> 8;
        u32 pk[4];
        #pragma unroll
        for (int j = 0; j < 4; ++j) {
            float lo = x[(size_t)(b0 + h * 8 + 2 * j    ) * N_IN + c];
            float hi = x[(size_t)(b0 + h * 8 + 2 * j + 1) * N_IN + c];
            pk[j] = pk2(lo, hi);
        }
        *(uint4*)((char*)vals + gbyte(c, h)) = make_uint4(pk[0], pk[1], pk[2], pk[3]);
    }
    __syncthreads();
    int row = 0, outoff = N_IN;
    #pragma unroll
    for (int li = 0; li < 5; ++li) {
        const int sz = (li < 4) ? 256 : 64;
        for (int n = tid; n < sz; n += 256) {
            const int gr = row + n;
            const int4*   s4 = (const int4*)(src + (size_t)gr * DEG);
            const float4* w4 = (const float4*)(w   + (size_t)gr * DEG);
            float acc[16];
            #pragma unroll
            for (int i = 0; i < 16; ++i) acc[i] = 0.f;
            #pragma unroll
            for (int k = 0; k < DEG / 4; ++k) {
                int4 i4 = s4[k]; float4 wv = w4[k];
                colacc16(vals, i4.x, wv.x, acc);
                colacc16(vals, i4.y, wv.y, acc);
                colacc16(vals, i4.z, wv.z, acc);
                colacc16(vals, i4.w, wv.w, acc);
            }
            const float bb = bias[gr], rr = resp[gr];
            u32 pk[8];
            #pragma unroll
            for (int j = 0; j < 8; ++j) {
                float lo = fmaxf(fmaf(rr, acc[2 * j    ], bb), 0.f);
                float hi = fmaxf(fmaf(rr, acc[2 * j + 1], bb), 0.f);
                pk[j] = pk2(lo, hi);
            }
            int ob = gbyte(outoff + n, 0);
            *(uint4*)((char*)vals + ob)      = make_uint4(pk[0], pk[1], pk[2], pk[3]);
            *(uint4*)((char*)vals + ob + 16) = make_uint4(pk[4], pk[5], pk[6], pk[7]);
        }
        __syncthreads();
        row += sz; outoff += sz;
    }
    #pragma unroll
    for (int i = 0; i < 4; ++i) {
        int idx = tid + i * 256;
        int c = idx & 63, b = idx >> 6;
        int col = TOTALW - 64 + c;
        const u32* g = (const u32*)((const char*)vals + gbyte(col, b >> 3));
        u32 d = g[(b & 7) >> 1];
        float v = (b & 1) ? __uint_as_float(d & 0xffff0000u)
                          : __uint_as_float(d << 16);
        out[(size_t)(b0 + b) * 64 + c] = v;
    }
}

extern "C" void kernel_launch(void* const* d_in, const int* in_sizes, int n_in,
                              void* d_out, int out_size, void* d_ws, size_t ws_size,
                              hipStream_t stream) {
    const float* x    = (const float*)d_in[0];
    const float* w    = (const float*)d_in[1];
    const float* bias = (const float*)d_in[2];
    const float* resp = (const float*)d_in[3];
    const int*   src  = (const int*)d_in[4];
    float* out = (float*)d_out;

    const int batch = in_sizes[0] / N_IN;            // 8192
    const size_t need = 737280ull * 2;               // dense B, bf16

    if (ws_size >= need && (batch % TILE_B) == 0) {
        u16* Bbuf = (u16*)d_ws;
        build_dense4<<<360, 256, 0, stream>>>(src, w, Bbuf);
        neat_mfma<<<batch / TILE_B, 512, 0, stream>>>(x, Bbuf, bias, resp, out);
    } else {
        neat_eval_r4<<<batch / FTILE_B, 256, 0, stream>>>(x, w, bias, resp, src, out);
    }
}

// Round 8
// 29.562 us; speedup vs baseline: 1.9616x; 1.0179x over previous
//
#include <hip/hip_runtime.h>

#define N_IN   256
#define N_EVAL 1088
#define TOTALW 1344
#define DEG    32

typedef __attribute__((ext_vector_type(8))) short short8;
typedef __attribute__((ext_vector_type(4))) float f32x4;
typedef unsigned short u16;
typedef unsigned int   u32;

__device__ __forceinline__ u32 pk2(float lo, float hi) {
    u32 ul = __float_as_uint(lo);
    u32 uh = __float_as_uint(hi);
    ul = (ul + 0x7fffu + ((ul >> 16) & 1u)) >> 16;
    uh = (uh + 0x7fffu + ((uh >> 16) & 1u)) & 0xffff0000u;
    return ul | uh;
}
__device__ __forceinline__ u16 bf1(float v) {
    u32 u = __float_as_uint(v);
    return (u16)((u + 0x7fffu + ((u >> 16) & 1u)) >> 16);
}

// ---------------- dense build: one thread per output u32 (2 bf16) ------------
// 368,640 threads, coalesced writes, per-wave input rows L1-resident.
// B bf16 layout: base + ((kt*NT + nt)*64 + lane)*8 + e ; u32 index == t.
__global__ __launch_bounds__(256) void build_dense32(
    const int* __restrict__ src, const float* __restrict__ w,
    u32* __restrict__ B32)
{
    const int t = blockIdx.x * 256 + threadIdx.x;    // 0..368639
    const int tile = t >> 8;                         // 0..1439
    const int q    = t & 255;
    const int lane = q >> 2;
    const int e2   = q & 3;
    int li, ts;
    if      (tile < 128)  { li = 0; ts = 0;    }
    else if (tile < 384)  { li = 1; ts = 128;  }
    else if (tile < 768)  { li = 2; ts = 384;  }
    else if (tile < 1280) { li = 3; ts = 768;  }
    else                  { li = 4; ts = 1280; }
    const int tloc = tile - ts;
    int kt, nt;
    if (li < 4) { kt = tloc >> 4; nt = tloc & 15; }
    else        { kt = tloc >> 2; nt = tloc & 3;  }
    const int ln = lane & 15, g = lane >> 4;
    const int gn = li * 256 + nt * 16 + ln;
    const int k0 = kt * 32 + g * 8 + e2 * 2;

    int c[DEG]; float ow[DEG];
    const int4*   s4 = (const int4*)(src + (size_t)gn * DEG);
    const float4* w4 = (const float4*)(w   + (size_t)gn * DEG);
    #pragma unroll
    for (int k = 0; k < 8; ++k) {
        int4 ci = s4[k]; float4 wf = w4[k];
        c[4*k+0]=ci.x; c[4*k+1]=ci.y; c[4*k+2]=ci.z; c[4*k+3]=ci.w;
        ow[4*k+0]=wf.x; ow[4*k+1]=wf.y; ow[4*k+2]=wf.z; ow[4*k+3]=wf.w;
    }
    float s0 = 0.f, s1 = 0.f;
    #pragma unroll
    for (int d = 0; d < DEG; ++d) {
        s0 += (c[d] == k0    ) ? ow[d] : 0.f;
        s1 += (c[d] == k0 + 1) ? ow[d] : 0.f;
    }
    B32[t] = pk2(s0, s1);
}

// ---------------- main MFMA kernel --------------------------------------------
#define TILE_B 32
#define LDSCOLS 1280
#define RSTRIDE (LDSCOLS * 2)        // 2560 B/row

#define MFMA(a, b, c) __builtin_amdgcn_mfma_f32_16x16x32_bf16(a, b, c, 0, 0, 0)

__global__ __launch_bounds__(512) void neat_mfma(
    const float* __restrict__ x, const u16* __restrict__ Bbuf,
    const float* __restrict__ bias, const float* __restrict__ resp,
    float* __restrict__ out)
{
    __shared__ uint4 ldsq[(TILE_B * RSTRIDE) / 16];   // 81,920 B
    __shared__ f32x4 pbuf[4 * 64 * 2];                // 8,192 B (layer-4 partials)
    char* lds = (char*)ldsq;
    const int tid  = threadIdx.x;
    const int b0   = blockIdx.x * TILE_B;
    const int lane = tid & 63;
    const int wvid = tid >> 6;

    const short8* Bf = (const short8*)Bbuf;
    // Depth-8 prefetch rings for the two B streams; layer-0 ring issued
    // BEFORE the x-staging barrier (loads complete under staging).
    short8 rp0[8], rp1[8];
    {
        const short8* bp0 = Bf + wvid * 64 + lane;           // li=0, nt0=wvid
        const short8* bp1 = Bf + (wvid + 8) * 64 + lane;     // li=0, nt1=wvid+8
        #pragma unroll
        for (int j = 0; j < 8; ++j) {
            rp0[j] = bp0[j * 1024];                          // STEP = 16*64
            rp1[j] = bp1[j * 1024];
        }
    }

    // stage x: f32 -> bf16, row-major, XOR-swizzled 16B granules
    #pragma unroll
    for (int i = 0; i < 4; ++i) {
        int f4 = tid + i * 512;          // 2048 = 32 rows x 64 float4
        int row = f4 >> 6;
        int c4  = f4 & 63;
        float4 xv = ((const float4*)(x + (size_t)(b0 + row) * N_IN))[c4];
        u32 p0 = pk2(xv.x, xv.y), p1 = pk2(xv.z, xv.w);
        int byte = row * RSTRIDE + ((c4 * 8) ^ ((row & 7) << 4));
        *(u32*)(lds + byte)     = p0;
        *(u32*)(lds + byte + 4) = p1;
    }
    __syncthreads();

    const int r0  = lane & 15;
    const int g16 = (lane >> 4) << 4;
    const int sw  = (r0 & 7) << 4;
    const int ab0 = r0 * RSTRIDE;
    const int ab1 = (r0 + 16) * RSTRIDE;

    int cbase = N_IN;
    #pragma unroll
    for (int li = 0; li < 5; ++li) {
        const int ktn = (N_IN + li * 256) >> 5;      // 8,16,24,32,40
        const int loff8[5] = {0, 8192, 24576, 49152, 81920};
        const int lo8 = loff8[li];
        const int nbase = cbase - N_IN;

        if (li < 4) {
            const int STEP = 16 * 64;                // NT=16
            const int nt0 = wvid, nt1 = wvid + 8;
            const short8* bp0 = Bf + lo8 + nt0 * 64 + lane;
            const short8* bp1 = Bf + lo8 + nt1 * 64 + lane;
            if (li != 0) {
                #pragma unroll
                for (int j = 0; j < 8; ++j) {
                    rp0[j] = bp0[j * STEP];
                    rp1[j] = bp1[j * STEP];
                }
            }
            // prefetch epilogue scalars while MFMAs run
            const int gr0 = nbase + nt0 * 16 + r0;
            const int gr1 = nbase + nt1 * 16 + r0;
            const float bb0 = bias[gr0], rr0 = resp[gr0];
            const float bb1 = bias[gr1], rr1 = resp[gr1];

            f32x4 acc00 = {0,0,0,0}, acc01 = {0,0,0,0};
            f32x4 acc10 = {0,0,0,0}, acc11 = {0,0,0,0};
            for (int kt8 = 0; kt8 < ktn; kt8 += 8) {
                #pragma unroll
                for (int j = 0; j < 8; ++j) {
                    int kt  = kt8 + j;
                    int ktp = kt + 8; if (ktp >= ktn) ktp = ktn - 1;
                    short8 f0 = bp0[ktp * STEP];
                    short8 f1 = bp1[ktp * STEP];
                    int inrow = (kt * 64 + g16) ^ sw;
                    short8 a0 = *(const short8*)(lds + ab0 + inrow);
                    short8 a1 = *(const short8*)(lds + ab1 + inrow);
                    acc00 = MFMA(a0, rp0[j], acc00);
                    acc01 = MFMA(a1, rp0[j], acc01);
                    acc10 = MFMA(a0, rp1[j], acc10);
                    acc11 = MFMA(a1, rp1[j], acc11);
                    rp0[j] = f0; rp1[j] = f1;
                }
            }
            #pragma unroll
            for (int t = 0; t < 2; ++t) {
                int nt = t ? nt1 : nt0;
                f32x4 aA = t ? acc10 : acc00;    // rows 0..15
                f32x4 aB = t ? acc11 : acc01;    // rows 16..31
                float bb = t ? bb1 : bb0;
                float rr = t ? rr1 : rr0;
                int colbyte = (cbase + nt * 16 + r0) * 2;
                #pragma unroll
                for (int r = 0; r < 4; ++r) {
                    int i0 = ((lane >> 4) << 2) + r;
                    float v0 = fmaxf(fmaf(rr, aA[r], bb), 0.f);
                    *(u16*)(lds + i0 * RSTRIDE + (colbyte ^ ((i0 & 7) << 4))) = bf1(v0);
                    int i1 = i0 + 16;
                    float v1 = fmaxf(fmaf(rr, aB[r], bb), 0.f);
                    *(u16*)(lds + i1 * RSTRIDE + (colbyte ^ ((i1 & 7) << 4))) = bf1(v1);
                }
            }
            __syncthreads();
        } else {
            // layer 4: 64 neurons, ktn=40; nt = wvid&3, K split across wave pairs
            const int STEP = 4 * 64;                 // NT=4
            const int nt0   = wvid & 3;
            const int ktbeg = (wvid >> 2) * 20;
            const int ktend = ktbeg + 20;
            const short8* bp0 = Bf + lo8 + nt0 * 64 + lane;
            #pragma unroll
            for (int j = 0; j < 4; ++j) rp0[j] = bp0[(ktbeg + j) * STEP];
            const int gr0 = nbase + nt0 * 16 + r0;
            const float bb0 = bias[gr0], rr0 = resp[gr0];

            f32x4 acc0 = {0,0,0,0}, acc1 = {0,0,0,0};
            for (int kt4 = ktbeg; kt4 < ktend; kt4 += 4) {
                #pragma unroll
                for (int j = 0; j < 4; ++j) {
                    int kt  = kt4 + j;
                    int ktp = kt + 4; if (ktp >= ktend) ktp = ktend - 1;
                    short8 f0 = bp0[ktp * STEP];
                    int inrow = (kt * 64 + g16) ^ sw;
                    short8 a0 = *(const short8*)(lds + ab0 + inrow);
                    short8 a1 = *(const short8*)(lds + ab1 + inrow);
                    acc0 = MFMA(a0, rp0[j], acc0);
                    acc1 = MFMA(a1, rp0[j], acc1);
                    rp0[j] = f0;
                }
            }
            if (wvid >= 4) {
                pbuf[((wvid - 4) * 64 + lane) * 2 + 0] = acc0;
                pbuf[((wvid - 4) * 64 + lane) * 2 + 1] = acc1;
            }
            __syncthreads();
            if (wvid < 4) {
                f32x4 q0 = pbuf[(wvid * 64 + lane) * 2 + 0];
                f32x4 q1 = pbuf[(wvid * 64 + lane) * 2 + 1];
                acc0 += q0; acc1 += q1;
                int col = nt0 * 16 + r0;
                #pragma unroll
                for (int r = 0; r < 4; ++r) {
                    int i0 = ((lane >> 4) << 2) + r;
                    out[(size_t)(b0 + i0) * 64 + col] = fmaxf(fmaf(rr0, acc0[r], bb0), 0.f);
                    int i1 = i0 + 16;
                    out[(size_t)(b0 + i1) * 64 + col] = fmaxf(fmaf(rr0, acc1[r], bb0), 0.f);
                }
            }
        }
        cbase += 256;
    }
}

// ---------------- R4 fallback (LDS gather, proven) ----------------------------
#define FTILE_B 16
__device__ __forceinline__ int gbyte(int c, int h) {
    return ((c << 5) + (h << 4)) ^ (int)((((unsigned)c >> 2) & 7u) << 5);
}
__device__ __forceinline__ void fmadw(u32 d, float wv, float* acc) {
    acc[0] = fmaf(__uint_as_float(d << 16), wv, acc[0]);
    acc[1] = fmaf(__uint_as_float(d & 0xffff0000u), wv, acc[1]);
}
__device__ __forceinline__ void colacc16(const u32* vals, int c, float wv, float* acc) {
    const uint4* p = (const uint4*)((const char*)vals + gbyte(c, 0));
    uint4 a = p[0]; uint4 b = p[1];
    fmadw(a.x, wv, acc + 0);  fmadw(a.y, wv, acc + 2);
    fmadw(a.z, wv, acc + 4);  fmadw(a.w, wv, acc + 6);
    fmadw(b.x, wv, acc + 8);  fmadw(b.y, wv, acc + 10);
    fmadw(b.z, wv, acc + 12); fmadw(b.w, wv, acc + 14);
}
__global__ __launch_bounds__(256) void neat_eval_r4(
    const float* __restrict__ x, const float* __restrict__ w,
    const float* __restrict__ bias, const float* __restrict__ resp,
    const int* __restrict__ src, float* __restrict__ out)
{
    __shared__ u32 vals[TOTALW * 8];
    const int tid = threadIdx.x;
    const int b0  = blockIdx.x * FTILE_B;
    #pragma unroll
    for (int i = 0; i < 2; ++i) {
        int g = tid + i * 256;
        int c = g & 255, h = g >> 8;
        u32 pk[4];
        #pragma unroll
        for (int j = 0; j < 4; ++j) {
            float lo = x[(size_t)(b0 + h * 8 + 2 * j    ) * N_IN + c];
            float hi = x[(size_t)(b0 + h * 8 + 2 * j + 1) * N_IN + c];
            pk[j] = pk2(lo, hi);
        }
        *(uint4*)((char*)vals + gbyte(c, h)) = make_uint4(pk[0], pk[1], pk[2], pk[3]);
    }
    __syncthreads();
    int row = 0, outoff = N_IN;
    #pragma unroll
    for (int li = 0; li < 5; ++li) {
        const int sz = (li < 4) ? 256 : 64;
        for (int n = tid; n < sz; n += 256) {
            const int gr = row + n;
            const int4*   s4 = (const int4*)(src + (size_t)gr * DEG);
            const float4* w4 = (const float4*)(w   + (size_t)gr * DEG);
            float acc[16];
            #pragma unroll
            for (int i = 0; i < 16; ++i) acc[i] = 0.f;
            #pragma unroll
            for (int k = 0; k < DEG / 4; ++k) {
                int4 i4 = s4[k]; float4 wv = w4[k];
                colacc16(vals, i4.x, wv.x, acc);
                colacc16(vals, i4.y, wv.y, acc);
                colacc16(vals, i4.z, wv.z, acc);
                colacc16(vals, i4.w, wv.w, acc);
            }
            const float bb = bias[gr], rr = resp[gr];
            u32 pk[8];
            #pragma unroll
            for (int j = 0; j < 8; ++j) {
                float lo = fmaxf(fmaf(rr, acc[2 * j    ], bb), 0.f);
                float hi = fmaxf(fmaf(rr, acc[2 * j + 1], bb), 0.f);
                pk[j] = pk2(lo, hi);
            }
            int ob = gbyte(outoff + n, 0);
            *(uint4*)((char*)vals + ob)      = make_uint4(pk[0], pk[1], pk[2], pk[3]);
            *(uint4*)((char*)vals + ob + 16) = make_uint4(pk[4], pk[5], pk[6], pk[7]);
        }
        __syncthreads();
        row += sz; outoff += sz;
    }
    #pragma unroll
    for (int i = 0; i < 4; ++i) {
        int idx = tid + i * 256;
        int c = idx & 63, b = idx >> 6;
        int col = TOTALW - 64 + c;
        const u32* g = (const u32*)((const char*)vals + gbyte(col, b >> 3));
        u32 d = g[(b & 7) >> 1];
        float v = (b & 1) ? __uint_as_float(d & 0xffff0000u)
                          : __uint_as_float(d << 16);
        out[(size_t)(b0 + b) * 64 + c] = v;
    }
}

extern "C" void kernel_launch(void* const* d_in, const int* in_sizes, int n_in,
                              void* d_out, int out_size, void* d_ws, size_t ws_size,
                              hipStream_t stream) {
    const float* x    = (const float*)d_in[0];
    const float* w    = (const float*)d_in[1];
    const float* bias = (const float*)d_in[2];
    const float* resp = (const float*)d_in[3];
    const int*   src  = (const int*)d_in[4];
    float* out = (float*)d_out;

    const int batch = in_sizes[0] / N_IN;            // 8192
    const size_t need = 737280ull * 2;               // dense B, bf16

    if (ws_size >= need && (batch % TILE_B) == 0) {
        u32* Bbuf = (u32*)d_ws;
        build_dense32<<<1440, 256, 0, stream>>>(src, w, Bbuf);
        neat_mfma<<<batch / TILE_B, 512, 0, stream>>>(x, (const u16*)Bbuf, bias, resp, out);
    } else {
        neat_eval_r4<<<batch / FTILE_B, 256, 0, stream>>>(x, w, bias, resp, src, out);
    }
}